// Round 3
// baseline (319.944 us; speedup 1.0000x reference)
//
#include <hip/hip_runtime.h>
#include <stdint.h>

#define NN 32768
#define DEG 16
#define CH 128
#define G4 512
#define MB 64          // nodes per LSTM block
#define BUF 32768      // byte stride between the two xh buffers

typedef short bf16x8 __attribute__((ext_vector_type(8)));
typedef float f32x4 __attribute__((ext_vector_type(4)));
typedef unsigned short u16;
typedef u16 u16x8 __attribute__((ext_vector_type(8)));
typedef uint32_t u32;

#define L2E  1.4426950408889634f
#define L2E2 2.8853900817779268f

__device__ __forceinline__ u16 f2bf(float f) {
  union { float f; uint32_t u; } v; v.f = f;
  uint32_t u = v.u;
  return (u16)((u + 0x7FFFu + ((u >> 16) & 1u)) >> 16);
}
__device__ __forceinline__ float exp2f_fast(float x) {
#if __has_builtin(__builtin_amdgcn_exp2f)
  return __builtin_amdgcn_exp2f(x);
#else
  float r; asm("v_exp_f32 %0, %1" : "=v"(r) : "v"(x)); return r;
#endif
}
__device__ __forceinline__ float rcpf_fast(float x) {
#if __has_builtin(__builtin_amdgcn_rcpf)
  return __builtin_amdgcn_rcpf(x);
#else
  float r; asm("v_rcp_f32 %0, %1" : "=v"(r) : "v"(x)); return r;
#endif
}
__device__ __forceinline__ u32 cvtpk(float lo, float hi) {
  u32 r; asm("v_cvt_pk_bf16_f32 %0, %1, %2" : "=v"(r) : "v"(lo), "v"(hi));
  return r;
}

// ---------------- prep kernels ----------------
__global__ void k_cvt_bf16(const float* __restrict__ in, u16* __restrict__ out, int n8) {
  int i = blockIdx.x * blockDim.x + threadIdx.x;
  if (i >= n8) return;
  const float* pp = in + (size_t)i * 8;
  u16x8 o;
  #pragma unroll
  for (int j = 0; j < 8; ++j) o[j] = f2bf(pp[j]);
  *(u16x8*)(out + (size_t)i * 8) = o;
}

// weights/bias pre-scaled by log2e (2*log2e for gate g); NO negation —
// sigmoid uses exp2 with the free neg input modifier.
__global__ void k_pack_lstm(const float* __restrict__ wih, const float* __restrict__ whh,
                            const float* __restrict__ bih, const float* __restrict__ bhh,
                            u16* __restrict__ Wc, float* __restrict__ bs) {
  int idx = blockIdx.x * blockDim.x + threadIdx.x;   // 512*256
  int g = idx >> 8, k = idx & 255;
  int gate = g >> 7;
  float sc = (gate == 2) ? L2E2 : L2E;
  float v = (k < CH) ? wih[g * CH + k] : whh[g * CH + (k - CH)];
  Wc[g * 256 + k] = f2bf(v * sc);
  if (k == 0) bs[g] = (bih[g] + bhh[g]) * sc;
}

__global__ void k_pack_lin(const float* __restrict__ wl, const float* __restrict__ wr,
                           u16* __restrict__ W) {
  int idx = blockIdx.x * blockDim.x + threadIdx.x;   // 128*256
  int o = idx >> 8, k = idx & 255;
  float v = (k < CH) ? wl[o * CH + k] : wr[o * CH + (k - CH)];
  W[o * 256 + k] = f2bf(v);
}

// ---------------- LSTM aggregation ----------------
// 512 threads = 8 waves, 64 nodes/block, double-buffered [x_t|h] in LDS.
// One barrier per step; all DS addressing = base reg + compile-time offset.
// body macro: T runtime-uniform, RD/WR/ISLAST compile-time.
#define LSTM_BODY(T, RD, WR, ISLAST) do {                                      \
  __syncthreads();                                                             \
  bf16x8 xp0 = {}, xp1 = {};                                                   \
  if (!(ISLAST)) {                                                             \
    int s0_ = srcs[sidx + (T) + 1];                                            \
    int s1_ = srcs[sidx + 32 * DEG + (T) + 1];                                 \
    xp0 = *(const bf16x8*)(xin + (size_t)s0_ * CH + ckh);                      \
    xp1 = *(const bf16x8*)(xin + (size_t)s1_ * CH + ckh);                      \
  }                                                                            \
  _Pragma("unroll")                                                            \
  for (int mt = 0; mt < 4; ++mt) {                                             \
    const int pp = mt & 1;                                                     \
    __builtin_amdgcn_s_setprio(1);                                             \
    _Pragma("unroll")                                                          \
    for (int kt = 0; kt < 8; ++kt) {                                           \
      const bf16x8 A = *(const bf16x8*)(xhb + ((kt & 1) ? aB : aA)             \
                        + ((RD) + mt * 8192 + (kt >> 1) * 128));               \
      if (kt == 0) {                                                           \
        _Pragma("unroll")                                                      \
        for (int gt = 0; gt < 4; ++gt)                                         \
          acc[pp][gt] = __builtin_amdgcn_mfma_f32_16x16x32_bf16(               \
              A, Wf[gt][0], bias[gt], 0, 0, 0);                                \
      } else {                                                                 \
        _Pragma("unroll")                                                      \
        for (int gt = 0; gt < 4; ++gt)                                         \
          acc[pp][gt] = __builtin_amdgcn_mfma_f32_16x16x32_bf16(               \
              A, Wf[gt][kt], acc[pp][gt], 0, 0, 0);                            \
      }                                                                        \
    }                                                                          \
    __builtin_amdgcn_s_setprio(0);                                             \
    float hq[4];                                                               \
    _Pragma("unroll")                                                          \
    for (int q = 0; q < 4; ++q) {                                              \
      float si = rcpf_fast(1.0f + exp2f_fast(-acc[pp][0][q]));                 \
      float sf = rcpf_fast(1.0f + exp2f_fast(-acc[pp][1][q]));                 \
      float so = rcpf_fast(1.0f + exp2f_fast(-acc[pp][3][q]));                 \
      float gg = fmaf(-2.0f, rcpf_fast(1.0f + exp2f_fast(acc[pp][2][q])), 1.0f); \
      float c  = fmaf(sf, cst[mt][q], si * gg);                                \
      cst[mt][q] = c;                                                          \
      float tc = fmaf(-2.0f, rcpf_fast(1.0f + exp2f_fast(c * L2E2)), 1.0f);    \
      hq[q] = so * tc;                                                         \
    }                                                                          \
    u32 hp0 = cvtpk(hq[0], hq[1]);                                             \
    u32 hp1 = cvtpk(hq[2], hq[3]);                                             \
    if (!(ISLAST)) {                                                           \
      *(u16*)(xhb + h0a + ((WR) + mt * 8192)) = (u16)hp0;                      \
      *(u16*)(xhb + h1a + ((WR) + mt * 8192)) = (u16)(hp0 >> 16);              \
      *(u16*)(xhb + h2a + ((WR) + mt * 8192)) = (u16)hp1;                      \
      *(u16*)(xhb + h3a + ((WR) + mt * 8192)) = (u16)(hp1 >> 16);              \
    } else {                                                                   \
      u16* op_ = aggrp + mt * 16 * CH;                                         \
      op_[0 * CH] = (u16)hp0;                                                  \
      op_[1 * CH] = (u16)(hp0 >> 16);                                          \
      op_[2 * CH] = (u16)hp1;                                                  \
      op_[3 * CH] = (u16)(hp1 >> 16);                                          \
    }                                                                          \
  }                                                                            \
  if (!(ISLAST)) {                                                             \
    *(bf16x8*)(xhb + stg + (WR))         = xp0;                                \
    *(bf16x8*)(xhb + stg + (WR) + 16384) = xp1;                                \
  }                                                                            \
} while (0)

__global__ __launch_bounds__(512, 2)
void k_lstm(const u16* __restrict__ xin, const int* __restrict__ src,
            const u16* __restrict__ Wc, const float* __restrict__ bs,
            u16* __restrict__ aggr) {
  __shared__ u16 xh[2 * MB * 256];   // 64 KB, swizzled: byte = row*512 + (colb ^ ((row&7)<<4))
  __shared__ int srcs[MB * DEG];     // 4 KB
  char* xhb = (char*)xh;
  const int tid = threadIdx.x;
  const int lane = tid & 63;
  const int wave = tid >> 6;
  const int l15 = lane & 15;
  const int lg  = lane >> 4;
  const int nodeBase = blockIdx.x * MB;

  srcs[tid]       = src[nodeBase * DEG + tid];
  srcs[tid + 512] = src[nodeBase * DEG + tid + 512];

  // weight B-fragments (pre-scaled): row = gate*128 + wave*16 + l15
  bf16x8 Wf[4][8];
  {
    const u16* wp = Wc + (wave * 16 + l15) * 256 + lg * 8;
    #pragma unroll
    for (int gt = 0; gt < 4; ++gt)
      #pragma unroll
      for (int kt = 0; kt < 8; ++kt)
        Wf[gt][kt] = *(const bf16x8*)(wp + gt * (CH * 256) + kt * 32);
  }
  f32x4 bias[4];
  #pragma unroll
  for (int gt = 0; gt < 4; ++gt) {
    float b = bs[gt * CH + wave * 16 + l15];
    bias[gt] = { b, b, b, b };
  }

  // hoisted DS addresses (base regs; everything else is compile-time offset)
  const int aA = l15 * 512 + ((lg * 16) ^ ((l15 & 7) << 4));  // A-read, even kt
  const int aB = aA ^ 64;                                     // A-read, odd kt
  const int hcol = 256 + wave * 32 + l15 * 2;
  const int h0a = (lg * 4 + 0) * 512 + (hcol ^ ((((lg & 1) * 4) + 0) << 4));
  const int h1a = (lg * 4 + 1) * 512 + (hcol ^ ((((lg & 1) * 4) + 1) << 4));
  const int h2a = (lg * 4 + 2) * 512 + (hcol ^ ((((lg & 1) * 4) + 2) << 4));
  const int h3a = (lg * 4 + 3) * 512 + (hcol ^ ((((lg & 1) * 4) + 3) << 4));
  const int r   = tid >> 4;                    // staging row 0..31 (and +32)
  const int ck  = (tid & 15) << 4;             // byte chunk within row
  const int ckh = (tid & 15) * 8;              // u16 chunk within row
  const int stg  = r * 512 + (ck ^ ((r & 7) << 4));
  const int stgH = r * 512 + ((256 + ck) ^ ((r & 7) << 4));
  const int sidx = r * DEG;
  u16* aggrp = aggr + (size_t)(nodeBase + lg * 4) * CH + wave * 16 + l15;

  __syncthreads();                   // srcs visible
  {                                  // stage x_0 into buf0, zero its h-region
    int s0 = srcs[sidx];
    int s1 = srcs[sidx + 32 * DEG];
    bf16x8 v0 = *(const bf16x8*)(xin + (size_t)s0 * CH + ckh);
    bf16x8 v1 = *(const bf16x8*)(xin + (size_t)s1 * CH + ckh);
    *(bf16x8*)(xhb + stg)          = v0;
    *(bf16x8*)(xhb + stg + 16384)  = v1;
    bf16x8 z = {};
    *(bf16x8*)(xhb + stgH)         = z;
    *(bf16x8*)(xhb + stgH + 16384) = z;
  }

  float cst[4][4] = {{0.f}};
  f32x4 acc[2][4];

  #pragma unroll 1
  for (int tp = 0; tp < 7; ++tp) {
    LSTM_BODY(2 * tp,     0,   BUF, false);
    LSTM_BODY(2 * tp + 1, BUF, 0,   false);
  }
  LSTM_BODY(14, 0,   BUF, false);
  LSTM_BODY(15, BUF, 0,   true);
}

// ---------------- fused lin_l/lin_r ----------------
__global__ __launch_bounds__(256, 4)
void k_linear(const u16* __restrict__ aggr, const u16* __restrict__ xroot,
              const u16* __restrict__ W, const float* __restrict__ bl,
              u16* __restrict__ out_bf, float* __restrict__ out_f, int relu) {
  const int lane = threadIdx.x & 63;
  const int wave = threadIdx.x >> 6;
  const int l15 = lane & 15, lg = lane >> 4;
  const int rowBase = blockIdx.x * 64 + wave * 16;

  f32x4 acc[8];
  #pragma unroll
  for (int nt = 0; nt < 8; ++nt) {
    float b = bl[nt * 16 + l15];
    acc[nt] = { b, b, b, b };
  }
  #pragma unroll
  for (int kt = 0; kt < 8; ++kt) {
    const u16* ap = (kt < 4) ? (aggr  + (size_t)(rowBase + l15) * CH + kt * 32 + lg * 8)
                             : (xroot + (size_t)(rowBase + l15) * CH + (kt - 4) * 32 + lg * 8);
    bf16x8 A = *(const bf16x8*)ap;
    #pragma unroll
    for (int nt = 0; nt < 8; ++nt) {
      bf16x8 B = *(const bf16x8*)(W + (nt * 16 + l15) * 256 + kt * 32 + lg * 8);
      acc[nt] = __builtin_amdgcn_mfma_f32_16x16x32_bf16(A, B, acc[nt], 0, 0, 0);
    }
  }
  #pragma unroll
  for (int nt = 0; nt < 8; ++nt) {
    #pragma unroll
    for (int q = 0; q < 4; ++q) {
      float v = acc[nt][q];
      if (relu) v = fmaxf(v, 0.0f);
      int row = rowBase + lg * 4 + q;
      int col = nt * 16 + l15;
      if (out_bf) out_bf[(size_t)row * CH + col] = f2bf(v);
      else        out_f[(size_t)row * CH + col]  = v;
    }
  }
}

extern "C" void kernel_launch(void* const* d_in, const int* in_sizes, int n_in,
                              void* d_out, int out_size, void* d_ws, size_t ws_size,
                              hipStream_t stream) {
  (void)in_sizes; (void)n_in; (void)out_size; (void)ws_size;
  const float* x    = (const float*)d_in[0];
  const int*   ei   = (const int*)d_in[1];
  const float* w1ih = (const float*)d_in[2];
  const float* w1hh = (const float*)d_in[3];
  const float* b1ih = (const float*)d_in[4];
  const float* b1hh = (const float*)d_in[5];
  const float* w1l  = (const float*)d_in[6];
  const float* b1l  = (const float*)d_in[7];
  const float* w1r  = (const float*)d_in[8];
  const float* w2ih = (const float*)d_in[9];
  const float* w2hh = (const float*)d_in[10];
  const float* b2ih = (const float*)d_in[11];
  const float* b2hh = (const float*)d_in[12];
  const float* w2l  = (const float*)d_in[13];
  const float* b2l  = (const float*)d_in[14];
  const float* w2r  = (const float*)d_in[15];

  char* p = (char*)d_ws;
  u16* x_bf  = (u16*)p;  p += (size_t)NN * CH * 2;
  u16* h1_bf = (u16*)p;  p += (size_t)NN * CH * 2;
  u16* ag_bf = (u16*)p;  p += (size_t)NN * CH * 2;
  u16* Wc1   = (u16*)p;  p += G4 * 256 * 2;
  u16* Wc2   = (u16*)p;  p += G4 * 256 * 2;
  u16* Wl1   = (u16*)p;  p += CH * 256 * 2;
  u16* Wl2   = (u16*)p;  p += CH * 256 * 2;
  float* bs1 = (float*)p; p += G4 * 4;
  float* bs2 = (float*)p; p += G4 * 4;

  k_cvt_bf16<<<(NN * CH / 8 + 255) / 256, 256, 0, stream>>>(x, x_bf, NN * CH / 8);
  k_pack_lstm<<<G4, 256, 0, stream>>>(w1ih, w1hh, b1ih, b1hh, Wc1, bs1);
  k_pack_lstm<<<G4, 256, 0, stream>>>(w2ih, w2hh, b2ih, b2hh, Wc2, bs2);
  k_pack_lin<<<CH, 256, 0, stream>>>(w1l, w1r, Wl1);
  k_pack_lin<<<CH, 256, 0, stream>>>(w2l, w2r, Wl2);

  k_lstm<<<NN / MB, 512, 0, stream>>>(x_bf, ei, Wc1, bs1, ag_bf);
  k_linear<<<NN / 64, 256, 0, stream>>>(ag_bf, x_bf, Wl1, b1l, h1_bf, nullptr, 1);
  k_lstm<<<NN / MB, 512, 0, stream>>>(h1_bf, ei, Wc2, bs2, ag_bf);
  k_linear<<<NN / 64, 256, 0, stream>>>(ag_bf, h1_bf, Wl2, b2l, nullptr, (float*)d_out, 0);
}